// Round 1
// baseline (1157.369 us; speedup 1.0000x reference)
//
#include <hip/hip_runtime.h>

// Problem constants (fixed by setup_inputs)
constexpr int B_ = 16, L_ = 2048, C_ = 256, K_ = 64, INNER_ = 4096;
constexpr int NCH = 16;          // L-chunks for mu partials
constexpr int RPB = L_ / NCH;    // 128 rows per k_em block
#define EPSF 1e-6f

typedef __attribute__((ext_vector_type(8))) short bf16x8;
typedef __attribute__((ext_vector_type(4))) float f32x4;

__device__ __forceinline__ unsigned short f2bf(float f) {
  union { float f; unsigned u; } v; v.f = f;
  unsigned r = v.u + 0x7fffu + ((v.u >> 16) & 1u);   // RNE
  return (unsigned short)(r >> 16);
}

// ---------------------------------------------------------------- k_pre
// casts w1,w2 -> bf16; BN fold; mu0 broadcast
__global__ __launch_bounds__(256) void k_pre(
    const float* __restrict__ w1, const float* __restrict__ w2,
    const float* __restrict__ gamma, const float* __restrict__ beta,
    const float* __restrict__ bmean, const float* __restrict__ bvar,
    const float* __restrict__ b1, const float* __restrict__ mu0,
    unsigned short* __restrict__ w1bf, unsigned short* __restrict__ w2bf,
    float* __restrict__ bnsc, float* __restrict__ bnsh, float* __restrict__ muB)
{
  int i = blockIdx.x * 256 + threadIdx.x;        // grid covers 1048576
  if (i < INNER_ * C_) {
    w1bf[i] = f2bf(w1[i]);
    w2bf[i] = f2bf(w2[i]);
  }
  if (i < K_ * C_ * B_) muB[i] = mu0[i & (K_ * C_ - 1)];
  if (i < INNER_) {
    float s = gamma[i] * rsqrtf(bvar[i] + 1e-5f);
    bnsc[i] = s;
    bnsh[i] = fmaf(b1[i] - bmean[i], s, beta[i]);  // absorbs b1
  }
}

// ---------------------------------------------------------------- k_xT
// x [B][L][C] -> xT [B][C][L]
__global__ __launch_bounds__(256) void k_xT(const float* __restrict__ x, float* __restrict__ xT)
{
  __shared__ float ts[64][65];
  int l0 = blockIdx.x * 64, c0 = blockIdx.y * 64, b = blockIdx.z;
  int t = threadIdx.x;
  for (int p = 0; p < 16; ++p) {
    int e = t + p * 256; int i = e >> 6, j = e & 63;
    ts[i][j] = x[((size_t)b * L_ + l0 + i) * C_ + c0 + j];
  }
  __syncthreads();
  for (int p = 0; p < 16; ++p) {
    int e = t + p * 256; int i2 = e >> 6, j2 = e & 63;
    xT[((size_t)b * C_ + c0 + i2) * L_ + l0 + j2] = ts[j2][i2];
  }
}

// ---------------------------------------------------------------- k_em
// fused: logits(x.muT) -> softmax(K) -> z ; colsum partial ; mu-update partials
template<bool DO_MU>
__global__ __launch_bounds__(256) void k_em(
    const float* __restrict__ xT,   // [B][C][L]
    const float* __restrict__ x,    // [B][L][C]
    const float* __restrict__ mu,   // [B][K][C]
    float* __restrict__ zout,       // [B][L][K]  (softmax, un-normalized over L)
    float* __restrict__ cp,         // [NCH][B*K] per-block colsum partials
    float* __restrict__ part)       // [NCH][B][K][C]
{
  __shared__ float mu_s[K_ * C_];        // 64KB
  __shared__ float z_s[RPB][K_ + 4];     // padded rows
  __shared__ float red[2][RPB];
  __shared__ float cpart[4][K_];

  int t = threadIdx.x;
  int b = blockIdx.y;
  int l0 = blockIdx.x * RPB;

  { // stage mu (b) into LDS
    const float4* msrc = (const float4*)(mu + (size_t)b * K_ * C_);
    float4* mdst = (float4*)mu_s;
    for (int e = t; e < K_ * C_ / 4; e += 256) mdst[e] = msrc[e];
  }
  __syncthreads();

  int r = t & (RPB - 1);
  int kh = t >> 7;                       // K-half (wave-uniform)

  // ---- logits: 32 dots over C, x from xT (coalesced), mu broadcast from LDS
  float acc[32];
#pragma unroll
  for (int i = 0; i < 32; ++i) acc[i] = 0.f;
  const float* xTb = xT + (size_t)b * C_ * L_ + l0 + r;
  for (int c4 = 0; c4 < C_ / 4; ++c4) {
    float xv0 = xTb[(size_t)(c4 * 4 + 0) * L_];
    float xv1 = xTb[(size_t)(c4 * 4 + 1) * L_];
    float xv2 = xTb[(size_t)(c4 * 4 + 2) * L_];
    float xv3 = xTb[(size_t)(c4 * 4 + 3) * L_];
#pragma unroll
    for (int kk = 0; kk < 32; ++kk) {
      float4 m4 = *(const float4*)(mu_s + (kh * 32 + kk) * C_ + c4 * 4);
      acc[kk] = fmaf(m4.x, xv0, acc[kk]);
      acc[kk] = fmaf(m4.y, xv1, acc[kk]);
      acc[kk] = fmaf(m4.z, xv2, acc[kk]);
      acc[kk] = fmaf(m4.w, xv3, acc[kk]);
    }
  }

  // ---- softmax over K=64 via 2-half LDS exchange
  float mx = acc[0];
#pragma unroll
  for (int i = 1; i < 32; ++i) mx = fmaxf(mx, acc[i]);
  red[kh][r] = mx;
  __syncthreads();
  float m = fmaxf(red[0][r], red[1][r]);
  float s = 0.f;
#pragma unroll
  for (int i = 0; i < 32; ++i) { acc[i] = __expf(acc[i] - m); s += acc[i]; }
  __syncthreads();
  red[kh][r] = s;
  __syncthreads();
  float inv = 1.f / (red[0][r] + red[1][r]);
#pragma unroll
  for (int i = 0; i < 32; ++i) acc[i] *= inv;

  // write z to LDS + global
  float* zo = zout + ((size_t)b * L_ + l0 + r) * K_ + kh * 32;
#pragma unroll
  for (int i = 0; i < 32; i += 4) {
    float4 v = make_float4(acc[i], acc[i + 1], acc[i + 2], acc[i + 3]);
    *(float4*)(&z_s[r][kh * 32 + i]) = v;
    *(float4*)(zo + i) = v;
  }
  __syncthreads();

  // ---- per-block colsum (deterministic)
  {
    int k = t & 63, q = t >> 6;
    float ps = 0.f;
#pragma unroll
    for (int rr = 0; rr < RPB / 4; ++rr) ps += z_s[q * (RPB / 4) + rr][k];
    cpart[q][k] = ps;
  }
  __syncthreads();
  if (t < K_) cp[(size_t)blockIdx.x * (B_ * K_) + b * K_ + t] =
      cpart[0][t] + cpart[1][t] + cpart[2][t] + cpart[3][t];

  // ---- mu-update partials: part[ch][b][k][c] = sum_l z[l][k]*x[l][c]
  if (DO_MU) {
    float acc2[K_];
#pragma unroll
    for (int i = 0; i < K_; ++i) acc2[i] = 0.f;
    const float* xb = x + ((size_t)b * L_ + l0) * C_ + t;
    for (int rr = 0; rr < RPB; ++rr) {
      float xv = xb[(size_t)rr * C_];
#pragma unroll
      for (int k4 = 0; k4 < K_ / 4; ++k4) {
        float4 z4 = *(const float4*)(&z_s[rr][k4 * 4]);
        acc2[k4 * 4 + 0] = fmaf(z4.x, xv, acc2[k4 * 4 + 0]);
        acc2[k4 * 4 + 1] = fmaf(z4.y, xv, acc2[k4 * 4 + 1]);
        acc2[k4 * 4 + 2] = fmaf(z4.z, xv, acc2[k4 * 4 + 2]);
        acc2[k4 * 4 + 3] = fmaf(z4.w, xv, acc2[k4 * 4 + 3]);
      }
    }
    float* pp = part + (((size_t)blockIdx.x * B_ + b) * K_) * C_ + t;
#pragma unroll
    for (int k = 0; k < K_; ++k) pp[(size_t)k * C_] = acc2[k];
  }
}

// ---------------------------------------------------------------- k_mufin
// reduce partials -> scale by 1/(eps+colsum) -> L2-normalize -> mu
template<bool WRITE_OUT>
__global__ __launch_bounds__(64) void k_mufin(
    const float* __restrict__ part, const float* __restrict__ cp,
    float* __restrict__ mu, float* __restrict__ zsA, float* __restrict__ outmu)
{
  int bk = blockIdx.x;     // b*64+k
  int t = threadIdx.x;     // 64
  float4 s = make_float4(0.f, 0.f, 0.f, 0.f);
#pragma unroll
  for (int ch = 0; ch < NCH; ++ch) {
    const float4* p = (const float4*)(part + ((size_t)ch * (B_ * K_) + bk) * C_);
    float4 v = p[t];
    s.x += v.x; s.y += v.y; s.z += v.z; s.w += v.w;
  }
  float zs = 0.f;
#pragma unroll
  for (int ch = 0; ch < NCH; ++ch) zs += cp[(size_t)ch * (B_ * K_) + bk];
  float sc = 1.f / (EPSF + zs);
  s.x *= sc; s.y *= sc; s.z *= sc; s.w *= sc;
  float ssq = s.x * s.x + s.y * s.y + s.z * s.z + s.w * s.w;
#pragma unroll
  for (int off = 32; off >= 1; off >>= 1) ssq += __shfl_xor(ssq, off, 64);
  float inv = 1.f / (EPSF + sqrtf(ssq));
  s.x *= inv; s.y *= inv; s.z *= inv; s.w *= inv;
  ((float4*)(mu + (size_t)bk * C_))[t] = s;
  if (WRITE_OUT) ((float4*)(outmu + (size_t)bk * C_))[t] = s;
  if (t == 0) zsA[bk] = zs;
}

// ---------------------------------------------------------------- k_attn
// attn[b][0][k][l] = zB[b][l][k] / (eps + colsum_k)
__global__ __launch_bounds__(256) void k_attn(
    const float* __restrict__ zB, const float* __restrict__ cpB, float* __restrict__ attn)
{
  __shared__ float zt[64][68];
  __shared__ float inv_s[K_];
  int b = blockIdx.y, l0 = blockIdx.x * 64;
  int t = threadIdx.x;
  if (t < K_) {
    float zs = 0.f;
#pragma unroll
    for (int ch = 0; ch < NCH; ++ch) zs += cpB[(size_t)ch * (B_ * K_) + b * K_ + t];
    inv_s[t] = 1.f / (EPSF + zs);
  }
  for (int p = 0; p < 16; ++p) {
    int e = t + p * 256; int lo = e >> 6, k = e & 63;
    zt[lo][k] = zB[((size_t)b * L_ + l0 + lo) * K_ + k];
  }
  __syncthreads();
  int lo = t & 63, kb = t >> 6;
  for (int p = 0; p < 16; ++p) {
    int k = kb * 16 + p;
    attn[((size_t)b * K_ + k) * L_ + l0 + lo] = zt[lo][k] * inv_s[k];
  }
}

// ---------------------------------------------------------------- k_recon
// recon[l][c] = sum_k znorm[l][k] * mu[k][c]  -> bf16
__global__ __launch_bounds__(256) void k_recon(
    const float* __restrict__ zA, const float* __restrict__ zsA,
    const float* __restrict__ mu, unsigned short* __restrict__ reconbf)
{
  __shared__ float mu_s[K_ * C_];   // 64KB
  __shared__ float zn[16][68];
  __shared__ float zinv[K_];
  int b = blockIdx.y, l0 = blockIdx.x * 128;
  int t = threadIdx.x;
  {
    const float4* msrc = (const float4*)(mu + (size_t)b * K_ * C_);
    for (int e = t; e < K_ * C_ / 4; e += 256) ((float4*)mu_s)[e] = msrc[e];
  }
  if (t < K_) zinv[t] = 1.f / (EPSF + zsA[b * K_ + t]);
  __syncthreads();
  for (int batch = 0; batch < 8; ++batch) {
    for (int e = t; e < 1024; e += 256) {
      int rr = e >> 6, k = e & 63;
      zn[rr][k] = zA[((size_t)b * L_ + l0 + batch * 16 + rr) * K_ + k] * zinv[k];
    }
    __syncthreads();
    for (int rr = 0; rr < 16; ++rr) {
      float a = 0.f;
#pragma unroll
      for (int k4 = 0; k4 < 16; ++k4) {
        float4 z4 = *(const float4*)(&zn[rr][k4 * 4]);
        a = fmaf(z4.x, mu_s[(k4 * 4 + 0) * C_ + t], a);
        a = fmaf(z4.y, mu_s[(k4 * 4 + 1) * C_ + t], a);
        a = fmaf(z4.z, mu_s[(k4 * 4 + 2) * C_ + t], a);
        a = fmaf(z4.w, mu_s[(k4 * 4 + 3) * C_ + t], a);
      }
      reconbf[((size_t)b * L_ + l0 + batch * 16 + rr) * C_ + t] = f2bf(a);
    }
    __syncthreads();
  }
}

// ---------------------------------------------------------------- k_mlp
// fused: out = relu(bn(recon @ w1^T)) @ w2^T + b2, bf16 MFMA 16x16x32
__global__ __launch_bounds__(256, 2) void k_mlp(
    const unsigned short* __restrict__ reconbf,  // [BL][256]
    const unsigned short* __restrict__ w1bf,     // [4096][256]
    const unsigned short* __restrict__ w2bf,     // [256][4096]
    const float* __restrict__ bnsc, const float* __restrict__ bnsh,
    const float* __restrict__ b2, float* __restrict__ outr)  // [BL][256]
{
  __shared__ unsigned short w1s[64 * 256];   // 32KB [i_loc][c], c8 ^= (i&3)
  __shared__ unsigned short w2s[256 * 64];   // 32KB [o][i_loc], i8 ^= (o&3)
  __shared__ unsigned short hs[64 * 64];     // 8KB  [row][i_loc], i8 ^= (row&3)

  int t = threadIdx.x;
  int w = t >> 6, lane = t & 63;
  int l15 = lane & 15, l4 = lane >> 4;
  int rb = blockIdx.x * 64;
  int wm = w & 1, wi = w >> 1;

  // persistent A1 fragments (recon rows for this wave's 2 m-tiles)
  bf16x8 a1[2][8];
#pragma unroll
  for (int mt = 0; mt < 2; ++mt)
#pragma unroll
    for (int ck = 0; ck < 8; ++ck)
      a1[mt][ck] = *(const bf16x8*)(reconbf +
          ((size_t)(rb + wm * 32 + mt * 16 + l15)) * C_ + ck * 32 + l4 * 8);

  f32x4 zero4 = {0.f, 0.f, 0.f, 0.f};
  f32x4 acc2[4][4];
#pragma unroll
  for (int mt = 0; mt < 4; ++mt)
#pragma unroll
    for (int nt = 0; nt < 4; ++nt) acc2[mt][nt] = zero4;

  for (int ic = 0; ic < INNER_ / 64; ++ic) {
    __syncthreads();   // protect prev-iter LDS reads
    // stage w1 chunk [64][256]
    {
      const uint4* s1 = (const uint4*)(w1bf + (size_t)ic * 64 * C_);
#pragma unroll
      for (int j = 0; j < 8; ++j) {
        int e = t + j * 256;
        int i = e >> 5, c8 = e & 31;
        *(uint4*)(w1s + i * 256 + (c8 ^ (i & 3)) * 8) = s1[e];
      }
#pragma unroll
      for (int j = 0; j < 8; ++j) {
        int e = t + j * 256;
        int o = e >> 3, i8 = e & 7;
        *(uint4*)(w2s + o * 64 + (i8 ^ (o & 3)) * 8) =
            *(const uint4*)(w2bf + (size_t)o * INNER_ + ic * 64 + i8 * 8);
      }
    }
    __syncthreads();

    // GEMM1: h[64][64] quadrant per wave (rows wm*32, cols wi*32)
    f32x4 acc1[2][2];
#pragma unroll
    for (int mt = 0; mt < 2; ++mt)
#pragma unroll
      for (int it = 0; it < 2; ++it) acc1[mt][it] = zero4;
#pragma unroll
    for (int ck = 0; ck < 8; ++ck) {
#pragma unroll
      for (int it = 0; it < 2; ++it) {
        int iloc = wi * 32 + it * 16 + l15;
        int c8 = ck * 4 + l4;
        bf16x8 bfr = *(const bf16x8*)(w1s + iloc * 256 + (c8 ^ (iloc & 3)) * 8);
#pragma unroll
        for (int mt = 0; mt < 2; ++mt)
          acc1[mt][it] = __builtin_amdgcn_mfma_f32_16x16x32_bf16(
              a1[mt][ck], bfr, acc1[mt][it], 0, 0, 0);
      }
    }

    // BN + ReLU + bf16 -> hs
#pragma unroll
    for (int mt = 0; mt < 2; ++mt) {
#pragma unroll
      for (int it = 0; it < 2; ++it) {
        int iloc = wi * 32 + it * 16 + l15;
        int ig = ic * 64 + iloc;
        float sc = bnsc[ig], sh = bnsh[ig];
        int i8 = iloc >> 3;
#pragma unroll
        for (int j = 0; j < 4; ++j) {
          int row = wm * 32 + mt * 16 + l4 * 4 + j;
          float v = fmaxf(fmaf(acc1[mt][it][j], sc, sh), 0.f);
          hs[row * 64 + (i8 ^ (row & 3)) * 8 + (iloc & 7)] = f2bf(v);
        }
      }
    }
    __syncthreads();

    // GEMM2: acc2 += h @ w2^T, wave owns o-range w*64..+63, all 4 m-tiles
#pragma unroll
    for (int kt = 0; kt < 2; ++kt) {
      bf16x8 a2[4];
#pragma unroll
      for (int mt = 0; mt < 4; ++mt) {
        int row = mt * 16 + l15;
        int i8 = kt * 4 + l4;
        a2[mt] = *(const bf16x8*)(hs + row * 64 + (i8 ^ (row & 3)) * 8);
      }
#pragma unroll
      for (int nt = 0; nt < 4; ++nt) {
        int o = w * 64 + nt * 16 + l15;
        int i8 = kt * 4 + l4;
        bf16x8 b2f = *(const bf16x8*)(w2s + o * 64 + (i8 ^ (o & 3)) * 8);
#pragma unroll
        for (int mt = 0; mt < 4; ++mt)
          acc2[mt][nt] = __builtin_amdgcn_mfma_f32_16x16x32_bf16(
              a2[mt], b2f, acc2[mt][nt], 0, 0, 0);
      }
    }
  }

  // epilogue: + b2, store f32
#pragma unroll
  for (int nt = 0; nt < 4; ++nt) {
    int o = w * 64 + nt * 16 + l15;
    float bias = b2[o];
#pragma unroll
    for (int mt = 0; mt < 4; ++mt) {
#pragma unroll
      for (int j = 0; j < 4; ++j) {
        int row = rb + mt * 16 + l4 * 4 + j;
        outr[(size_t)row * C_ + o] = acc2[mt][nt][j] + bias;
      }
    }
  }
}

// ---------------------------------------------------------------- launch
extern "C" void kernel_launch(void* const* d_in, const int* in_sizes, int n_in,
                              void* d_out, int out_size, void* d_ws, size_t ws_size,
                              hipStream_t stream)
{
  const float* x     = (const float*)d_in[0];
  const float* mu0   = (const float*)d_in[2];
  const float* w1    = (const float*)d_in[3];
  const float* b1    = (const float*)d_in[4];
  const float* gamma = (const float*)d_in[5];
  const float* beta  = (const float*)d_in[6];
  const float* bmean = (const float*)d_in[7];
  const float* bvar  = (const float*)d_in[8];
  const float* w2    = (const float*)d_in[9];
  const float* b2    = (const float*)d_in[10];
  float* out = (float*)d_out;

  float* ws = (float*)d_ws;
  float* muB  = ws + 0;         // 262144
  float* zA   = ws + 262144;    // 2097152
  float* zB   = ws + 2359296;   // 2097152
  float* zsA  = ws + 4456448;   // 1024
  float* cpA  = ws + 4457472;   // 16384
  float* cpB  = ws + 4473856;   // 16384
  float* bnsc = ws + 4490240;   // 4096
  float* bnsh = ws + 4494336;   // 4096
  float* part = ws + 4498432;   // 4194304
  float* xT   = ws + 8692736;   // 8388608
  unsigned short* reconbf = (unsigned short*)(ws + 17081344);  // 4194304 bf16
  unsigned short* w1bf    = (unsigned short*)(ws + 19178496);  // 1048576 bf16
  unsigned short* w2bf    = (unsigned short*)(ws + 19702784);  // 1048576 bf16
  // total: 20227072 floats = 80.9 MB

  k_pre<<<4096, 256, 0, stream>>>(w1, w2, gamma, beta, bmean, bvar, b1, mu0,
                                  w1bf, w2bf, bnsc, bnsh, muB);
  k_xT<<<dim3(32, 4, 16), 256, 0, stream>>>(x, xT);

  for (int s = 0; s < 10; ++s) {
    k_em<true><<<dim3(NCH, B_), 256, 0, stream>>>(xT, x, muB, zA, cpA, part);
    if (s == 9) k_mufin<true ><<<1024, 64, 0, stream>>>(part, cpA, muB, zsA, out);
    else        k_mufin<false><<<1024, 64, 0, stream>>>(part, cpA, muB, zsA, out);
  }
  // new_z with final mu
  k_em<false><<<dim3(NCH, B_), 256, 0, stream>>>(xT, x, muB, zB, cpB, part);
  k_attn<<<dim3(32, B_), 256, 0, stream>>>(zB, cpB, out + 262144);
  k_recon<<<dim3(16, B_), 256, 0, stream>>>(zA, zsA, muB, reconbf);
  k_mlp<<<512, 256, 0, stream>>>(reconbf, w1bf, w2bf, bnsc, bnsh, b2, out + 2359296);
}